// Round 2
// baseline (284.312 us; speedup 1.0000x reference)
//
#include <hip/hip_runtime.h>

#define TOK 8192   // B*S
#define DIM 512    // D
#define NE  32     // experts
#define KTOT (NE * DIM)

#define BM 128
#define BN 128
#define BK 64

typedef float f32x4  __attribute__((ext_vector_type(4)));
typedef float f32x16 __attribute__((ext_vector_type(16)));
typedef short s16x8  __attribute__((ext_vector_type(8)));

typedef const void __attribute__((address_space(1)))* gp1_t;
typedef void __attribute__((address_space(3)))* lp3_t;

__device__ __forceinline__ void gl_lds16(const void* g, void* l) {
    __builtin_amdgcn_global_load_lds((gp1_t)g, (lp3_t)l, 16, 0, 0);
}

// stage one 16KB tile (128 rows x 128B) with 256 threads: 4 rounds of 16B
__device__ __forceinline__ void stage4(const ushort* g, size_t gstride, char* l) {
    gl_lds16(g,               l);
    gl_lds16(g + gstride,     l + 4096);
    gl_lds16(g + 2 * gstride, l + 8192);
    gl_lds16(g + 3 * gstride, l + 12288);
}

// counted-vmcnt barrier (T3/T4): never drain to 0 in the main loop.
template<int N>
__device__ __forceinline__ void wait_bar() {
    asm volatile("s_waitcnt vmcnt(%0) lgkmcnt(0)" :: "n"(N) : "memory");
    __builtin_amdgcn_s_barrier();
}

__device__ __forceinline__ ushort f2bf(float f) {
    unsigned u = __builtin_bit_cast(unsigned, f);
    unsigned r = (u + 0x7fffu + ((u >> 16) & 1u)) >> 16;
    return (ushort)r;
}

// ---- fused prep: blocks [0,2048) transpose+convert W; [2048,3072) gates+cvt x
__global__ __launch_bounds__(256) void k_prep(const float* __restrict__ w,
                                              ushort* __restrict__ wt,
                                              const float* __restrict__ x,
                                              const float* __restrict__ gw,
                                              const float* __restrict__ gb,
                                              float* __restrict__ G,
                                              ushort* __restrict__ xb) {
    __shared__ __align__(16) char smem[64 * 65 * 4];
    const int bx = blockIdx.x;
    const int tid = threadIdx.x;
    if (bx < 2048) {
        // ---- Wt[f][e*512+d] = bf16(w[e][d][f]), 64x64 tile ----
        float (*tile)[65] = (float(*)[65])smem;
        const int e = bx >> 6;
        const int f0 = ((bx >> 3) & 7) * 64;
        const int d0 = (bx & 7) * 64;
        const int tx = tid & 63, ty = tid >> 6;  // ty 0..3
        const float* we = w + (size_t)e * DIM * DIM;
#pragma unroll
        for (int i = ty; i < 64; i += 4)
            tile[i][tx] = we[(size_t)(d0 + i) * DIM + f0 + tx];
        __syncthreads();
#pragma unroll
        for (int i = ty; i < 64; i += 4)
            wt[(size_t)(f0 + i) * KTOT + e * DIM + d0 + tx] = f2bf(tile[tx][i]);
    } else {
        // ---- gates (8 tokens/block, shfl softmax) + x -> bf16 ----
        float* xs = (float*)smem;
        const int t0 = (bx - 2048) * 8;
        const float* xBase = x + (size_t)t0 * DIM;
#pragma unroll
        for (int k = 0; k < 4; ++k) {
            int i4 = (k * 256 + tid) * 4;
            float4 v = *(const float4*)(xBase + i4);
            xs[i4 + 0] = v.x; xs[i4 + 1] = v.y; xs[i4 + 2] = v.z; xs[i4 + 3] = v.w;
            ushort4 o;
            o.x = f2bf(v.x); o.y = f2bf(v.y); o.z = f2bf(v.z); o.w = f2bf(v.w);
            *(ushort4*)(xb + (size_t)t0 * DIM + i4) = o;
        }
        __syncthreads();
        const int tok = tid >> 5;   // 0..7
        const int e = tid & 31;
        float l = gb[e];
        const float* xr = xs + tok * DIM;
#pragma unroll 8
        for (int d = 0; d < DIM; ++d)
            l += xr[d] * gw[d * NE + e];
        float mx = l;
#pragma unroll
        for (int m = 16; m >= 1; m >>= 1) mx = fmaxf(mx, __shfl_xor(mx, m));
        float ex = expf(l - mx);
        float s = ex;
#pragma unroll
        for (int m = 16; m >= 1; m >>= 1) s += __shfl_xor(s, m);
        G[(size_t)(t0 + tok) * NE + e] = ex / s;
    }
}

// ------------- main GEMM v3: counted-vmcnt deep pipeline -------------
// v2 established the iter cadence (2780 cyc) is barrier-drain latency, not
// LDS BW / matrix: __syncthreads' vmcnt(0) forced the one-ahead DMA to
// complete within each iter. v3: Bs 3-deep ring, B(g+2) issued at iter g,
// s_waitcnt vmcnt(4/8) + raw s_barrier (never 0 except last iter). As is
// single-buffered: A-frags live in regs per kt; A(kt+1) staged at ee==1.
// Fragment reads / MFMA / fold / epilogue identical to verified v2.
// Wait-count derivation (4 gl_lds ops per stage4, per-wave counts):
//   need B(g), issued at iter g-2. Ops issued after it: B(g+1) [4] always,
//   plus A(kt+1) [4] if staged in iters g-2/g-1 (ee==2 or ee==3, kt<7).
//   -> N=8 at ee in {2,3} && kt<7; N=0 at the final iter; else N=4.
__global__ __launch_bounds__(256, 2) void k_moe_gemm(const ushort* __restrict__ xb,
                                                     const ushort* __restrict__ wt,
                                                     const float* __restrict__ G,
                                                     float* __restrict__ out0,
                                                     float* __restrict__ out1) {
    __shared__ __align__(16) ushort As[BM * BK];      // 16 KB (single buffer)
    __shared__ __align__(16) ushort Bs[3][BN * BK];   // 3 x 16 KB ring
    __shared__ float Gs[16][BM];                      // 8 KB

    const int tid = threadIdx.x;
    const int m0 = blockIdx.y * BM;
    const int n0 = blockIdx.x * BN;
    const int e0 = blockIdx.z * 16;
    float* __restrict__ dst = blockIdx.z ? out1 : out0;

    for (int i = tid; i < 16 * BM; i += 256) {
        int e = i >> 7, r = i & 127;
        Gs[e][r] = G[(size_t)(m0 + r) * NE + e0 + e];
    }

    const int lane = tid & 63;
    const int wave = tid >> 6;          // 0..3
    const int wm = (wave & 1) * 64;
    const int wn = (wave >> 1) * 64;
    const int l31 = lane & 31;
    const int hi = lane >> 5;           // 0..1
    const int key = l31 & 7;

    // frag read offsets: row*128 + ((2s+hi) ^ (row&7))*16  (row&7 == key)
    int chunkOff[4], rowOffA[2], rowOffB[2];
#pragma unroll
    for (int s = 0; s < 4; ++s) chunkOff[s] = ((2 * s + hi) ^ key) * 16;
#pragma unroll
    for (int i = 0; i < 2; ++i) {
        rowOffA[i] = (wm + i * 32 + l31) * 128;
        rowOffB[i] = (wn + i * 32 + l31) * 128;
    }

    // staging map: 256 thr x 16B = 4KB/round, 4 rounds per 16KB tile
    const int srow = tid >> 3;                       // 0..31 (+32/round)
    const int scol = ((tid & 7) ^ (srow & 7)) * 8;   // swizzled global column
    const ushort* aBase = xb + (size_t)(m0 + srow) * DIM + scol;
    const ushort* bBase = wt + (size_t)(n0 + srow) * KTOT + (size_t)e0 * DIM + scol;
    const int ldsOff = tid * 16;

    f32x16 zv16;
#pragma unroll
    for (int j = 0; j < 16; ++j) zv16[j] = 0.f;
    f32x16 acc[2][2];
#pragma unroll
    for (int i = 0; i < 2; ++i)
#pragma unroll
        for (int j = 0; j < 2; ++j) acc[i][j] = zv16;

    // prologue: A(kt=0) -> As; B tiles 0,1 -> ring slots 0,1; full drain once.
    stage4(aBase, (size_t)32 * DIM, (char*)As + ldsOff);
    stage4(bBase, (size_t)32 * KTOT, (char*)Bs[0] + ldsOff);
    stage4(bBase + (size_t)1 * DIM, (size_t)32 * KTOT, (char*)Bs[1] + ldsOff);
    asm volatile("s_waitcnt vmcnt(0) lgkmcnt(0)" ::: "memory");
    __builtin_amdgcn_s_barrier();

    // rotating ring pointers (named, not runtime-indexed: rule #20)
    char* Br0 = (char*)Bs[0];   // tile g
    char* Br1 = (char*)Bs[1];   // tile g+1
    char* Br2 = (char*)Bs[2];   // DMA target for tile g+2

    s16x8 areg[2][4];

#pragma unroll 1
    for (int kt = 0; kt < 8; ++kt) {
#pragma unroll 1
        for (int ee = 0; ee < 16; ++ee) {
            const int g = kt * 16 + ee;

            // publish tile g (counted wait, then barrier)
            if (kt == 7 && ee == 15)                  wait_bar<0>();
            else if (kt < 7 && (ee == 2 || ee == 3))  wait_bar<8>();
            else                                      wait_bar<4>();

            // issue B DMA two ahead into the slot freed at iter g-1
            const int gn = g + 2;
            if (gn < 128) {
                const ushort* bN = bBase + (size_t)(gn & 15) * DIM + (gn >> 4) * BK;
                stage4(bN, (size_t)32 * KTOT, Br2 + ldsOff);
            }
            // stage next kt's A once per kt (As is dead after ee==0's reads)
            if (ee == 1 && kt < 7)
                stage4(aBase + (kt + 1) * BK, (size_t)32 * DIM, (char*)As + ldsOff);

            // A fragments -> registers at kt start, reused for 16 experts
            if (ee == 0) {
#pragma unroll
                for (int mi = 0; mi < 2; ++mi)
#pragma unroll
                    for (int s = 0; s < 4; ++s)
                        areg[mi][s] = *(const s16x8*)((const char*)As + rowOffA[mi] + chunkOff[s]);
            }

            s16x8 breg[2][4];
#pragma unroll
            for (int nj = 0; nj < 2; ++nj)
#pragma unroll
                for (int s = 0; s < 4; ++s)
                    breg[nj][s] = *(const s16x8*)(Br0 + rowOffB[nj] + chunkOff[s]);

#pragma unroll
            for (int mi = 0; mi < 2; ++mi) {
                f32x16 p0 = __builtin_amdgcn_mfma_f32_32x32x16_bf16(areg[mi][0], breg[0][0], zv16, 0, 0, 0);
                f32x16 p1 = __builtin_amdgcn_mfma_f32_32x32x16_bf16(areg[mi][0], breg[1][0], zv16, 0, 0, 0);
#pragma unroll
                for (int s = 1; s < 4; ++s) {
                    p0 = __builtin_amdgcn_mfma_f32_32x32x16_bf16(areg[mi][s], breg[0][s], p0, 0, 0, 0);
                    p1 = __builtin_amdgcn_mfma_f32_32x32x16_bf16(areg[mi][s], breg[1][s], p1, 0, 0, 0);
                }
                // fold with per-token gates; Gs reads are 2-address broadcasts
#pragma unroll
                for (int gq = 0; gq < 4; ++gq) {
                    const f32x4 gt = *(const f32x4*)&Gs[ee][wm + mi * 32 + 8 * gq + 4 * hi];
#pragma unroll
                    for (int j = 0; j < 4; ++j) {
                        acc[mi][0][4 * gq + j] += gt[j] * p0[4 * gq + j];
                        acc[mi][1][4 * gq + j] += gt[j] * p1[4 * gq + j];
                    }
                }
            }

            // rotate ring: g+1 becomes current, freed slot becomes DMA target
            char* t = Br0; Br0 = Br1; Br1 = Br2; Br2 = t;
        }
    }

    // epilogue: C/D layout col=lane&31, row=(reg&3)+8*(reg>>2)+4*hi
#pragma unroll
    for (int mi = 0; mi < 2; ++mi)
#pragma unroll
        for (int nj = 0; nj < 2; ++nj) {
            const int col = n0 + wn + nj * 32 + l31;
#pragma unroll
            for (int gq = 0; gq < 4; ++gq) {
                float* p = dst + (size_t)(m0 + wm + mi * 32 + 8 * gq + 4 * hi) * DIM + col;
                p[0 * DIM] = acc[mi][nj][4 * gq + 0];
                p[1 * DIM] = acc[mi][nj][4 * gq + 1];
                p[2 * DIM] = acc[mi][nj][4 * gq + 2];
                p[3 * DIM] = acc[mi][nj][4 * gq + 3];
            }
        }
}

// ---- deterministic two-phase sum: out += P (both fully written upstream) ----
__global__ __launch_bounds__(256) void k_reduce(float* __restrict__ out,
                                                const float* __restrict__ P) {
    int i = (blockIdx.x * 256 + threadIdx.x) * 4;
    float4 a = *(const float4*)(out + i);
    float4 b = *(const float4*)(P + i);
    a.x += b.x; a.y += b.y; a.z += b.z; a.w += b.w;
    *(float4*)(out + i) = a;
}

extern "C" void kernel_launch(void* const* d_in, const int* in_sizes, int n_in,
                              void* d_out, int out_size, void* d_ws, size_t ws_size,
                              hipStream_t stream) {
    const float* x  = (const float*)d_in[0];   // [8192][512]
    const float* gw = (const float*)d_in[1];   // [512][32]
    const float* gb = (const float*)d_in[2];   // [32]
    const float* w  = (const float*)d_in[3];   // [32][512][512]
    float* out = (float*)d_out;                // [8192][512] fp32

    char* ws = (char*)d_ws;
    ushort* xb = (ushort*)ws;                            //  0..8 MiB
    ushort* wt = (ushort*)(ws + (8u << 20));             //  8..24 MiB
    float*  G  = (float*)(ws + (24u << 20));             // 24..25 MiB
    float*  P  = (float*)(ws + (25u << 20));             // 25..41 MiB

    k_prep<<<dim3(2048 + TOK / 8), dim3(256), 0, stream>>>(w, wt, x, gw, gb, G, xb);
    k_moe_gemm<<<dim3(DIM / BN, TOK / BM, 2), dim3(256), 0, stream>>>(xb, wt, G, out, P);
    k_reduce<<<dim3(TOK * DIM / 1024), dim3(256), 0, stream>>>(out, P);
}

// Round 3
// 262.137 us; speedup vs baseline: 1.0846x; 1.0846x over previous
//
#include <hip/hip_runtime.h>

#define TOK 8192   // B*S
#define DIM 512    // D
#define NE  32     // experts
#define KTOT (NE * DIM)

#define BM 256
#define BN 128
#define BK 64

typedef float f32x4  __attribute__((ext_vector_type(4)));
typedef float f32x16 __attribute__((ext_vector_type(16)));
typedef short s16x8  __attribute__((ext_vector_type(8)));

typedef const void __attribute__((address_space(1)))* gp1_t;
typedef void __attribute__((address_space(3)))* lp3_t;

__device__ __forceinline__ void gl_lds16(const void* g, void* l) {
    __builtin_amdgcn_global_load_lds((gp1_t)g, (lp3_t)l, 16, 0, 0);
}

// A tile: 256 rows x 128B = 32KB; 512 thr x 16B = 8KB/round -> 4 rounds
__device__ __forceinline__ void stageA(const ushort* g, char* l) {
    gl_lds16(g,                      l);
    gl_lds16(g + (size_t) 64 * DIM,  l + 8192);
    gl_lds16(g + (size_t)128 * DIM,  l + 16384);
    gl_lds16(g + (size_t)192 * DIM,  l + 24576);
}
// B tile: 128 rows x 128B = 16KB -> 2 rounds
__device__ __forceinline__ void stageB(const ushort* g, char* l) {
    gl_lds16(g,                      l);
    gl_lds16(g + (size_t)64 * KTOT,  l + 8192);
}

__device__ __forceinline__ ushort f2bf(float f) {
    unsigned u = __builtin_bit_cast(unsigned, f);
    unsigned r = (u + 0x7fffu + ((u >> 16) & 1u)) >> 16;
    return (ushort)r;
}

// ---- fused prep: blocks [0,2048) transpose+convert W; [2048,3072) gates+cvt x
__global__ __launch_bounds__(256) void k_prep(const float* __restrict__ w,
                                              ushort* __restrict__ wt,
                                              const float* __restrict__ x,
                                              const float* __restrict__ gw,
                                              const float* __restrict__ gb,
                                              float* __restrict__ G,
                                              ushort* __restrict__ xb) {
    __shared__ __align__(16) char smem[64 * 65 * 4];
    const int bx = blockIdx.x;
    const int tid = threadIdx.x;
    if (bx < 2048) {
        // ---- Wt[f][e*512+d] = bf16(w[e][d][f]), 64x64 tile ----
        float (*tile)[65] = (float(*)[65])smem;
        const int e = bx >> 6;
        const int f0 = ((bx >> 3) & 7) * 64;
        const int d0 = (bx & 7) * 64;
        const int tx = tid & 63, ty = tid >> 6;  // ty 0..3
        const float* we = w + (size_t)e * DIM * DIM;
#pragma unroll
        for (int i = ty; i < 64; i += 4)
            tile[i][tx] = we[(size_t)(d0 + i) * DIM + f0 + tx];
        __syncthreads();
#pragma unroll
        for (int i = ty; i < 64; i += 4)
            wt[(size_t)(f0 + i) * KTOT + e * DIM + d0 + tx] = f2bf(tile[tx][i]);
    } else {
        // ---- gates (8 tokens/block, shfl softmax) + x -> bf16 ----
        float* xs = (float*)smem;
        const int t0 = (bx - 2048) * 8;
        const float* xBase = x + (size_t)t0 * DIM;
#pragma unroll
        for (int k = 0; k < 4; ++k) {
            int i4 = (k * 256 + tid) * 4;
            float4 v = *(const float4*)(xBase + i4);
            xs[i4 + 0] = v.x; xs[i4 + 1] = v.y; xs[i4 + 2] = v.z; xs[i4 + 3] = v.w;
            ushort4 o;
            o.x = f2bf(v.x); o.y = f2bf(v.y); o.z = f2bf(v.z); o.w = f2bf(v.w);
            *(ushort4*)(xb + (size_t)t0 * DIM + i4) = o;
        }
        __syncthreads();
        const int tok = tid >> 5;   // 0..7
        const int e = tid & 31;
        float l = gb[e];
        const float* xr = xs + tok * DIM;
#pragma unroll 8
        for (int d = 0; d < DIM; ++d)
            l += xr[d] * gw[d * NE + e];
        float mx = l;
#pragma unroll
        for (int m = 16; m >= 1; m >>= 1) mx = fmaxf(mx, __shfl_xor(mx, m));
        float ex = expf(l - mx);
        float s = ex;
#pragma unroll
        for (int m = 16; m >= 1; m >>= 1) s += __shfl_xor(s, m);
        G[(size_t)(t0 + tok) * NE + e] = ex / s;
    }
}

// ------------- main GEMM v4: BM=256 to halve the B-tile L3 stream -------------
// v0==v1 at 148.5us despite different LDS/MFMA profiles -> cadence set by the
// B-tile feed (32KB/CU/iter from L3, ~7 TB/s aggregate). v3's counted-vmcnt
// regressed -> reverted to the proven v2 sync (one-ahead DMA + __syncthreads).
// v4 changes ONLY geometry: BM=256, BN=128, 512 thr (4m x 2n waves of 64x64),
// 1 block/CU. Per-CU MFMA work unchanged; B DMA and gl_lds count halve.
// LDS: A dbuf 64KB + B dbuf 32KB + Gs 16KB = 112KB.
// C/D layout (32x32): col=lane&31, row=(reg&3)+8*(reg>>2)+4*(lane>>5).
// LDS XOR-swizzle: LDS[row][c] = Glob[row][c ^ (row&7)] (16B chunks).
__global__ __launch_bounds__(512, 2) void k_moe_gemm(const ushort* __restrict__ xb,
                                                     const ushort* __restrict__ wt,
                                                     const float* __restrict__ G,
                                                     float* __restrict__ out0,
                                                     float* __restrict__ out1) {
    __shared__ __align__(16) ushort As[2][BM * BK];   // 2 x 32 KB
    __shared__ __align__(16) ushort Bs[2][BN * BK];   // 2 x 16 KB
    __shared__ float Gs[16][BM];                      // 16 KB

    const int tid = threadIdx.x;
    const int m0 = blockIdx.y * BM;
    const int n0 = blockIdx.x * BN;
    const int e0 = blockIdx.z * 16;
    float* __restrict__ dst = blockIdx.z ? out1 : out0;

    for (int i = tid; i < 16 * BM; i += 512) {
        int e = i >> 8, r = i & 255;
        Gs[e][r] = G[(size_t)(m0 + r) * NE + e0 + e];
    }

    const int lane = tid & 63;
    const int wave = tid >> 6;          // 0..7
    const int wm = (wave & 3) * 64;     // 4 m-positions (0..192)
    const int wn = (wave >> 2) * 64;    // 2 n-positions (0,64)
    const int l31 = lane & 31;
    const int hi = lane >> 5;           // 0..1
    const int key = l31 & 7;

    // frag read offsets: row*128 + ((2s+hi) ^ (row&7))*16  (row&7 == key)
    int chunkOff[4], rowOffA[2], rowOffB[2];
#pragma unroll
    for (int s = 0; s < 4; ++s) chunkOff[s] = ((2 * s + hi) ^ key) * 16;
#pragma unroll
    for (int i = 0; i < 2; ++i) {
        rowOffA[i] = (wm + i * 32 + l31) * 128;
        rowOffB[i] = (wn + i * 32 + l31) * 128;
    }

    // staging map: 512 thr x 16B = 8KB/round
    const int srow = tid >> 3;                       // 0..63
    const int scol = ((tid & 7) ^ (srow & 7)) * 8;   // swizzled global column
    const ushort* aBase = xb + (size_t)(m0 + srow) * DIM + scol;
    const ushort* bBase = wt + (size_t)(n0 + srow) * KTOT + (size_t)e0 * DIM + scol;
    const int ldsOff = tid * 16;

    f32x16 zv16;
#pragma unroll
    for (int j = 0; j < 16; ++j) zv16[j] = 0.f;
    f32x16 acc[2][2];
#pragma unroll
    for (int i = 0; i < 2; ++i)
#pragma unroll
        for (int j = 0; j < 2; ++j) acc[i][j] = zv16;

    // prologue: stage A(kt=0) -> As[0], B(e=0,kt=0) -> Bs[0]
    stageA(aBase, (char*)As[0] + ldsOff);
    stageB(bBase, (char*)Bs[0] + ldsOff);
    __syncthreads();

#pragma unroll 1
    for (int kt = 0; kt < 8; ++kt) {
        // A fragments -> registers, reused for all 16 experts of this kt
        const char* Ab = (const char*)As[kt & 1];
        s16x8 areg[2][4];
#pragma unroll
        for (int mi = 0; mi < 2; ++mi)
#pragma unroll
            for (int s = 0; s < 4; ++s)
                areg[mi][s] = *(const s16x8*)(Ab + rowOffA[mi] + chunkOff[s]);

#pragma unroll 1
        for (int ee = 0; ee < 16; ++ee) {
            // issue next-tile DMA (one ahead); barrier at end publishes it
            const int gn = kt * 16 + ee + 1;
            if (gn < 128) {
                const ushort* bN = bBase + (size_t)(gn & 15) * DIM + (gn >> 4) * BK;
                stageB(bN, (char*)Bs[gn & 1] + ldsOff);
                if (ee == 15)
                    stageA(aBase + (kt + 1) * BK, (char*)As[(kt + 1) & 1] + ldsOff);
            }

            const char* Bb = (const char*)Bs[ee & 1];
            s16x8 breg[2][4];
#pragma unroll
            for (int nj = 0; nj < 2; ++nj)
#pragma unroll
                for (int s = 0; s < 4; ++s)
                    breg[nj][s] = *(const s16x8*)(Bb + rowOffB[nj] + chunkOff[s]);

#pragma unroll
            for (int mi = 0; mi < 2; ++mi) {
                f32x16 p0 = __builtin_amdgcn_mfma_f32_32x32x16_bf16(areg[mi][0], breg[0][0], zv16, 0, 0, 0);
                f32x16 p1 = __builtin_amdgcn_mfma_f32_32x32x16_bf16(areg[mi][0], breg[1][0], zv16, 0, 0, 0);
#pragma unroll
                for (int s = 1; s < 4; ++s) {
                    p0 = __builtin_amdgcn_mfma_f32_32x32x16_bf16(areg[mi][s], breg[0][s], p0, 0, 0, 0);
                    p1 = __builtin_amdgcn_mfma_f32_32x32x16_bf16(areg[mi][s], breg[1][s], p1, 0, 0, 0);
                }
                // fold with per-token gates; Gs reads are 2-address broadcasts
#pragma unroll
                for (int gq = 0; gq < 4; ++gq) {
                    const f32x4 gt = *(const f32x4*)&Gs[ee][wm + mi * 32 + 8 * gq + 4 * hi];
#pragma unroll
                    for (int j = 0; j < 4; ++j) {
                        acc[mi][0][4 * gq + j] += gt[j] * p0[4 * gq + j];
                        acc[mi][1][4 * gq + j] += gt[j] * p1[4 * gq + j];
                    }
                }
            }
            __syncthreads();   // publishes next buffers; DMA already complete
        }
    }

    // epilogue: C/D layout col=lane&31, row=(reg&3)+8*(reg>>2)+4*hi
#pragma unroll
    for (int mi = 0; mi < 2; ++mi)
#pragma unroll
        for (int nj = 0; nj < 2; ++nj) {
            const int col = n0 + wn + nj * 32 + l31;
#pragma unroll
            for (int gq = 0; gq < 4; ++gq) {
                float* p = dst + (size_t)(m0 + wm + mi * 32 + 8 * gq + 4 * hi) * DIM + col;
                p[0 * DIM] = acc[mi][nj][4 * gq + 0];
                p[1 * DIM] = acc[mi][nj][4 * gq + 1];
                p[2 * DIM] = acc[mi][nj][4 * gq + 2];
                p[3 * DIM] = acc[mi][nj][4 * gq + 3];
            }
        }
}

// ---- deterministic two-phase sum: out += P (both fully written upstream) ----
__global__ __launch_bounds__(256) void k_reduce(float* __restrict__ out,
                                                const float* __restrict__ P) {
    int i = (blockIdx.x * 256 + threadIdx.x) * 4;
    float4 a = *(const float4*)(out + i);
    float4 b = *(const float4*)(P + i);
    a.x += b.x; a.y += b.y; a.z += b.z; a.w += b.w;
    *(float4*)(out + i) = a;
}

extern "C" void kernel_launch(void* const* d_in, const int* in_sizes, int n_in,
                              void* d_out, int out_size, void* d_ws, size_t ws_size,
                              hipStream_t stream) {
    const float* x  = (const float*)d_in[0];   // [8192][512]
    const float* gw = (const float*)d_in[1];   // [512][32]
    const float* gb = (const float*)d_in[2];   // [32]
    const float* w  = (const float*)d_in[3];   // [32][512][512]
    float* out = (float*)d_out;                // [8192][512] fp32

    char* ws = (char*)d_ws;
    ushort* xb = (ushort*)ws;                            //  0..8 MiB
    ushort* wt = (ushort*)(ws + (8u << 20));             //  8..24 MiB
    float*  G  = (float*)(ws + (24u << 20));             // 24..25 MiB
    float*  P  = (float*)(ws + (25u << 20));             // 25..41 MiB

    k_prep<<<dim3(2048 + TOK / 8), dim3(256), 0, stream>>>(w, wt, x, gw, gb, G, xb);
    k_moe_gemm<<<dim3(DIM / BN, TOK / BM, 2), dim3(512), 0, stream>>>(xb, wt, G, out, P);
    k_reduce<<<dim3(TOK * DIM / 1024), dim3(256), 0, stream>>>(out, P);
}

// Round 4
// 256.754 us; speedup vs baseline: 1.1073x; 1.0210x over previous
//
#include <hip/hip_runtime.h>

#define TOK 8192   // B*S
#define DIM 512    // D
#define NE  32     // experts
#define KTOT (NE * DIM)

#define BM 256
#define BN 128
#define BK 128

typedef float f32x4  __attribute__((ext_vector_type(4)));
typedef float f32x16 __attribute__((ext_vector_type(16)));
typedef short s16x8  __attribute__((ext_vector_type(8)));

typedef const void __attribute__((address_space(1)))* gp1_t;
typedef void __attribute__((address_space(3)))* lp3_t;

__device__ __forceinline__ void gl_lds16(const void* g, void* l) {
    __builtin_amdgcn_global_load_lds((gp1_t)g, (lp3_t)l, 16, 0, 0);
}

// A tile: 256 rows x 256B = 64KB; 512 thr x 16B = 8KB/round -> 8 rounds
__device__ __forceinline__ void stageA(const ushort* g, char* l) {
#pragma unroll
    for (int r = 0; r < 8; ++r)
        gl_lds16(g + (size_t)r * 32 * DIM, l + r * 8192);
}
// B tile: 128 rows x 256B = 32KB -> 4 rounds
__device__ __forceinline__ void stageB(const ushort* g, char* l) {
#pragma unroll
    for (int r = 0; r < 4; ++r)
        gl_lds16(g + (size_t)r * 32 * KTOT, l + r * 8192);
}

__device__ __forceinline__ ushort f2bf(float f) {
    unsigned u = __builtin_bit_cast(unsigned, f);
    unsigned r = (u + 0x7fffu + ((u >> 16) & 1u)) >> 16;
    return (ushort)r;
}

// ---- fused prep: blocks [0,2048) transpose+convert W; [2048,3072) gates+cvt x
__global__ __launch_bounds__(256) void k_prep(const float* __restrict__ w,
                                              ushort* __restrict__ wt,
                                              const float* __restrict__ x,
                                              const float* __restrict__ gw,
                                              const float* __restrict__ gb,
                                              float* __restrict__ G,
                                              ushort* __restrict__ xb) {
    __shared__ __align__(16) char smem[64 * 65 * 4];
    const int bx = blockIdx.x;
    const int tid = threadIdx.x;
    if (bx < 2048) {
        // ---- Wt[f][e*512+d] = bf16(w[e][d][f]), 64x64 tile ----
        float (*tile)[65] = (float(*)[65])smem;
        const int e = bx >> 6;
        const int f0 = ((bx >> 3) & 7) * 64;
        const int d0 = (bx & 7) * 64;
        const int tx = tid & 63, ty = tid >> 6;  // ty 0..3
        const float* we = w + (size_t)e * DIM * DIM;
#pragma unroll
        for (int i = ty; i < 64; i += 4)
            tile[i][tx] = we[(size_t)(d0 + i) * DIM + f0 + tx];
        __syncthreads();
#pragma unroll
        for (int i = ty; i < 64; i += 4)
            wt[(size_t)(f0 + i) * KTOT + e * DIM + d0 + tx] = f2bf(tile[tx][i]);
    } else {
        // ---- gates (8 tokens/block, shfl softmax) + x -> bf16 ----
        float* xs = (float*)smem;
        const int t0 = (bx - 2048) * 8;
        const float* xBase = x + (size_t)t0 * DIM;
#pragma unroll
        for (int k = 0; k < 4; ++k) {
            int i4 = (k * 256 + tid) * 4;
            float4 v = *(const float4*)(xBase + i4);
            xs[i4 + 0] = v.x; xs[i4 + 1] = v.y; xs[i4 + 2] = v.z; xs[i4 + 3] = v.w;
            ushort4 o;
            o.x = f2bf(v.x); o.y = f2bf(v.y); o.z = f2bf(v.z); o.w = f2bf(v.w);
            *(ushort4*)(xb + (size_t)t0 * DIM + i4) = o;
        }
        __syncthreads();
        const int tok = tid >> 5;   // 0..7
        const int e = tid & 31;
        float l = gb[e];
        const float* xr = xs + tok * DIM;
#pragma unroll 8
        for (int d = 0; d < DIM; ++d)
            l += xr[d] * gw[d * NE + e];
        float mx = l;
#pragma unroll
        for (int m = 16; m >= 1; m >>= 1) mx = fmaxf(mx, __shfl_xor(mx, m));
        float ex = expf(l - mx);
        float s = ex;
#pragma unroll
        for (int m = 16; m >= 1; m >>= 1) s += __shfl_xor(s, m);
        G[(size_t)(t0 + tok) * NE + e] = ex / s;
    }
}

// --------- main GEMM v5: BK=128 -> 64 fat iterations (latency floor / 2) ----
// v1/v2/v4 all sat at ~2800 cyc per barrier-bounded iteration regardless of
// LDS volume, DMA volume, or blocks/CU -> per-iteration latency floor, not a
// throughput binder. v5 halves the iteration count: BK=128, 4 kt x 16 ee = 64
// iters, each with 2x MFMA (8-slice chains). Sync structure is the PROVEN
// v2/v4 one (one-ahead DMA + __syncthreads) -- v3's counted-vmcnt regressed.
// A: single 64KB buffer, frags in regs per kt (restage at ee==1, 15-iter
// slack; every iter's barrier drains vmcnt). B: 2x32KB dbuf. Gs: 16KB.
// Gates: 8 f32x4 register loads per ee, reused across nj.
// Row width now 256B (16 chunks); swizzle XORs low 3 bits of the 16B-chunk
// index: LDS[row][c] = Glob[row][c ^ (row&7)], reader chunk (2s+hi)^(l31&7).
// C/D layout (32x32): col=lane&31, row=(reg&3)+8*(reg>>2)+4*(lane>>5).
__global__ __launch_bounds__(512, 2) void k_moe_gemm(const ushort* __restrict__ xb,
                                                     const ushort* __restrict__ wt,
                                                     const float* __restrict__ G,
                                                     float* __restrict__ out0,
                                                     float* __restrict__ out1) {
    __shared__ __align__(16) ushort As[BM * BK];      // 64 KB (single buffer)
    __shared__ __align__(16) ushort Bs[2][BN * BK];   // 2 x 32 KB
    __shared__ float Gs[16][BM];                      // 16 KB

    const int tid = threadIdx.x;
    const int m0 = blockIdx.y * BM;
    const int n0 = blockIdx.x * BN;
    const int e0 = blockIdx.z * 16;
    float* __restrict__ dst = blockIdx.z ? out1 : out0;

    for (int i = tid; i < 16 * BM; i += 512) {
        int e = i >> 8, r = i & 255;
        Gs[e][r] = G[(size_t)(m0 + r) * NE + e0 + e];
    }

    const int lane = tid & 63;
    const int wave = tid >> 6;          // 0..7
    const int wm = (wave & 3) * 64;     // 4 m-positions (0..192)
    const int wn = (wave >> 2) * 64;    // 2 n-positions (0,64)
    const int l31 = lane & 31;
    const int hi = lane >> 5;           // 0..1
    const int key = l31 & 7;

    // frag read offsets: row*256 + ((2s+hi) ^ (row&7))*16   (row&7 == key)
    int chunkOff[8], rowOffA[2], rowOffB[2];
#pragma unroll
    for (int s = 0; s < 8; ++s) chunkOff[s] = ((2 * s + hi) ^ key) * 16;
#pragma unroll
    for (int i = 0; i < 2; ++i) {
        rowOffA[i] = (wm + i * 32 + l31) * 256;
        rowOffB[i] = (wn + i * 32 + l31) * 256;
    }

    // staging map: 512 thr x 16B = 8KB/round = 32 rows of 256B
    const int srow = tid >> 4;                        // 0..31 (+32/round)
    const int scol = ((tid & 15) ^ (srow & 7)) * 8;   // swizzled global col (ushorts)
    const ushort* aBase = xb + (size_t)(m0 + srow) * DIM + scol;
    const ushort* bBase = wt + (size_t)(n0 + srow) * KTOT + (size_t)e0 * DIM + scol;
    const int ldsOff = tid * 16;

    f32x16 zv16;
#pragma unroll
    for (int j = 0; j < 16; ++j) zv16[j] = 0.f;
    f32x16 acc[2][2];
#pragma unroll
    for (int i = 0; i < 2; ++i)
#pragma unroll
        for (int j = 0; j < 2; ++j) acc[i][j] = zv16;

    // prologue: stage A(kt=0), B(tile g=0) -> Bs[0]
    stageA(aBase, (char*)As + ldsOff);
    stageB(bBase, (char*)Bs[0] + ldsOff);
    __syncthreads();

    s16x8 areg[2][8];

#pragma unroll 1
    for (int kt = 0; kt < 4; ++kt) {
#pragma unroll 1
        for (int ee = 0; ee < 16; ++ee) {
            const int g = kt * 16 + ee;

            // issue next B tile (one ahead); barrier at end publishes it
            const int gn = g + 1;
            if (gn < 64) {
                const ushort* bN = bBase + (size_t)(gn & 15) * DIM + (gn >> 4) * BK;
                stageB(bN, (char*)Bs[gn & 1] + ldsOff);
            }
            // restage A for next kt (regs hold current kt; 15-iter slack)
            if (ee == 1 && kt < 3)
                stageA(aBase + (kt + 1) * BK, (char*)As + ldsOff);

            // A fragments -> registers at kt start, reused for 16 experts
            if (ee == 0) {
#pragma unroll
                for (int mi = 0; mi < 2; ++mi)
#pragma unroll
                    for (int s = 0; s < 8; ++s)
                        areg[mi][s] = *(const s16x8*)((const char*)As + rowOffA[mi] + chunkOff[s]);
            }

            // gates -> registers (8 b128 broadcasts, reused across nj)
            f32x4 greg[2][4];
#pragma unroll
            for (int mi = 0; mi < 2; ++mi)
#pragma unroll
                for (int gq = 0; gq < 4; ++gq)
                    greg[mi][gq] = *(const f32x4*)&Gs[ee][wm + mi * 32 + 8 * gq + 4 * hi];

            const char* Bb = (const char*)Bs[g & 1];
#pragma unroll
            for (int nj = 0; nj < 2; ++nj) {
                s16x8 breg[8];
#pragma unroll
                for (int s = 0; s < 8; ++s)
                    breg[s] = *(const s16x8*)(Bb + rowOffB[nj] + chunkOff[s]);

                f32x16 p0 = __builtin_amdgcn_mfma_f32_32x32x16_bf16(areg[0][0], breg[0], zv16, 0, 0, 0);
                f32x16 p1 = __builtin_amdgcn_mfma_f32_32x32x16_bf16(areg[1][0], breg[0], zv16, 0, 0, 0);
#pragma unroll
                for (int s = 1; s < 8; ++s) {
                    p0 = __builtin_amdgcn_mfma_f32_32x32x16_bf16(areg[0][s], breg[s], p0, 0, 0, 0);
                    p1 = __builtin_amdgcn_mfma_f32_32x32x16_bf16(areg[1][s], breg[s], p1, 0, 0, 0);
                }
#pragma unroll
                for (int gq = 0; gq < 4; ++gq) {
#pragma unroll
                    for (int j = 0; j < 4; ++j) {
                        acc[0][nj][4 * gq + j] += greg[0][gq][j] * p0[4 * gq + j];
                        acc[1][nj][4 * gq + j] += greg[1][gq][j] * p1[4 * gq + j];
                    }
                }
            }
            __syncthreads();   // publishes next buffers; DMA already complete
        }
    }

    // epilogue: C/D layout col=lane&31, row=(reg&3)+8*(reg>>2)+4*hi
#pragma unroll
    for (int mi = 0; mi < 2; ++mi)
#pragma unroll
        for (int nj = 0; nj < 2; ++nj) {
            const int col = n0 + wn + nj * 32 + l31;
#pragma unroll
            for (int gq = 0; gq < 4; ++gq) {
                float* p = dst + (size_t)(m0 + wm + mi * 32 + 8 * gq + 4 * hi) * DIM + col;
                p[0 * DIM] = acc[mi][nj][4 * gq + 0];
                p[1 * DIM] = acc[mi][nj][4 * gq + 1];
                p[2 * DIM] = acc[mi][nj][4 * gq + 2];
                p[3 * DIM] = acc[mi][nj][4 * gq + 3];
            }
        }
}

// ---- deterministic two-phase sum: out += P (both fully written upstream) ----
__global__ __launch_bounds__(256) void k_reduce(float* __restrict__ out,
                                                const float* __restrict__ P) {
    int i = (blockIdx.x * 256 + threadIdx.x) * 4;
    float4 a = *(const float4*)(out + i);
    float4 b = *(const float4*)(P + i);
    a.x += b.x; a.y += b.y; a.z += b.z; a.w += b.w;
    *(float4*)(out + i) = a;
}

extern "C" void kernel_launch(void* const* d_in, const int* in_sizes, int n_in,
                              void* d_out, int out_size, void* d_ws, size_t ws_size,
                              hipStream_t stream) {
    const float* x  = (const float*)d_in[0];   // [8192][512]
    const float* gw = (const float*)d_in[1];   // [512][32]
    const float* gb = (const float*)d_in[2];   // [32]
    const float* w  = (const float*)d_in[3];   // [32][512][512]
    float* out = (float*)d_out;                // [8192][512] fp32

    char* ws = (char*)d_ws;
    ushort* xb = (ushort*)ws;                            //  0..8 MiB
    ushort* wt = (ushort*)(ws + (8u << 20));             //  8..24 MiB
    float*  G  = (float*)(ws + (24u << 20));             // 24..25 MiB
    float*  P  = (float*)(ws + (25u << 20));             // 25..41 MiB

    k_prep<<<dim3(2048 + TOK / 8), dim3(256), 0, stream>>>(w, wt, x, gw, gb, G, xb);
    k_moe_gemm<<<dim3(DIM / BN, TOK / BM, 2), dim3(512), 0, stream>>>(xb, wt, G, out, P);
    k_reduce<<<dim3(TOK * DIM / 1024), dim3(256), 0, stream>>>(out, P);
}